// Round 1
// baseline (731.792 us; speedup 1.0000x reference)
//
#include <hip/hip_runtime.h>
#include <hip/hip_bf16.h>

#define SEQ 2305
#define NROWS 4610      // B*SEQ
#define DIM 512
#define QKVN 1536

typedef __attribute__((ext_vector_type(8))) short v8s;
typedef __attribute__((ext_vector_type(4))) float v4f;

__device__ __forceinline__ float wave_max(float x) {
    for (int o = 32; o; o >>= 1) x = fmaxf(x, __shfl_xor(x, o));
    return x;
}
__device__ __forceinline__ float wave_sum(float x) {
    for (int o = 32; o; o >>= 1) x += __shfl_xor(x, o);
    return x;
}

// ---------------- copy / convert ----------------
__global__ void copy_f32v4(const float4* __restrict__ in, float4* __restrict__ out, int n4) {
    int i = blockIdx.x * blockDim.x + threadIdx.x;
    if (i < n4) out[i] = in[i];
}

__global__ void f32_to_bf16(const float* __restrict__ in, __hip_bfloat16* __restrict__ out, int n) {
    int i = blockIdx.x * blockDim.x + threadIdx.x;
    if (i < n) out[i] = __float2bfloat16(in[i]);
}

// ---------------- weight transpose + bf16 convert ----------------
struct WPack { const float* p[12]; };

__global__ void transpose_weights(WPack wp, __hip_bfloat16* __restrict__ wqkv,
                                  __hip_bfloat16* __restrict__ wo) {
    __shared__ float tile[32][33];
    int m = blockIdx.z;
    const float* src = wp.p[m];
    int l = m >> 2, j = m & 3;
    __hip_bfloat16* dst = (j < 3) ? (wqkv + (size_t)l * QKVN * DIM + (size_t)j * DIM * DIM)
                                  : (wo + (size_t)l * DIM * DIM);
    int bx = blockIdx.x * 32, by = blockIdx.y * 32;
    int tx = threadIdx.x, ty = threadIdx.y;
    #pragma unroll
    for (int i = 0; i < 4; i++)
        tile[ty + 8 * i][tx] = src[(size_t)(by + ty + 8 * i) * DIM + bx + tx];
    __syncthreads();
    #pragma unroll
    for (int i = 0; i < 4; i++)
        dst[(size_t)(bx + ty + 8 * i) * DIM + by + tx] = __float2bfloat16(tile[tx][ty + 8 * i]);
}

// ---------------- bf16 MFMA GEMM: C[M,N] = A[M,K] * Bt[N,K]^T (+bias +res) ----------------
// K fixed = 512. Block: 256 thr = 4 waves in 2x2, each wave 32x32 via 2x2 mfma 16x16x32.
__global__ __launch_bounds__(256) void gemm_bf16(
    const __hip_bfloat16* __restrict__ A, const __hip_bfloat16* __restrict__ Bt,
    float* __restrict__ C, const float* __restrict__ bias, const float* __restrict__ res,
    int M, int N) {
    const int K = 512;
    int tid = threadIdx.x;
    int wid = tid >> 6, lane = tid & 63;
    int quad = lane >> 4, l16 = lane & 15;
    int waveM = blockIdx.x * 64 + (wid >> 1) * 32;
    int waveN = blockIdx.y * 64 + (wid & 1) * 32;

    const short* As = (const short*)A;
    const short* Bs = (const short*)Bt;

    int rowA0 = waveM + l16;        if (rowA0 >= M) rowA0 = M - 1;
    int rowA1 = waveM + 16 + l16;   if (rowA1 >= M) rowA1 = M - 1;
    int rowB0 = waveN + l16;
    int rowB1 = waveN + 16 + l16;

    const short* a0p = As + (size_t)rowA0 * K + quad * 8;
    const short* a1p = As + (size_t)rowA1 * K + quad * 8;
    const short* b0p = Bs + (size_t)rowB0 * K + quad * 8;
    const short* b1p = Bs + (size_t)rowB1 * K + quad * 8;

    v4f acc00 = {}, acc01 = {}, acc10 = {}, acc11 = {};
    #pragma unroll 4
    for (int k0 = 0; k0 < K; k0 += 32) {
        v8s a0 = *(const v8s*)(a0p + k0);
        v8s a1 = *(const v8s*)(a1p + k0);
        v8s b0 = *(const v8s*)(b0p + k0);
        v8s b1 = *(const v8s*)(b1p + k0);
        acc00 = __builtin_amdgcn_mfma_f32_16x16x32_bf16(a0, b0, acc00, 0, 0, 0);
        acc01 = __builtin_amdgcn_mfma_f32_16x16x32_bf16(a0, b1, acc01, 0, 0, 0);
        acc10 = __builtin_amdgcn_mfma_f32_16x16x32_bf16(a1, b0, acc10, 0, 0, 0);
        acc11 = __builtin_amdgcn_mfma_f32_16x16x32_bf16(a1, b1, acc11, 0, 0, 0);
    }

    v4f accs[2][2] = {{acc00, acc01}, {acc10, acc11}};
    #pragma unroll
    for (int sm = 0; sm < 2; sm++)
        #pragma unroll
        for (int sn = 0; sn < 2; sn++)
            #pragma unroll
            for (int r = 0; r < 4; r++) {
                int row = waveM + sm * 16 + quad * 4 + r;
                int col = waveN + sn * 16 + l16;
                if (row < M) {
                    float v = accs[sm][sn][r];
                    if (bias) v += bias[col];
                    if (res) v += res[(size_t)row * N + col];
                    C[(size_t)row * N + col] = v;
                }
            }
}

// ---------------- axial attention (typ 0/1) ----------------
// grid: (48, 16) blocks of 256. One block per (n, b, h). qkv fp32 [4610][1536].
__global__ __launch_bounds__(256) void axial_attn(
    const float* __restrict__ qkv, __hip_bfloat16* __restrict__ attn_b, int typ) {
    __shared__ float kl[49 * 65];
    __shared__ float vl[49 * 65];
    __shared__ float pl[4][64];
    int n = blockIdx.x;
    int b = blockIdx.y >> 3, h = blockIdx.y & 7;
    int tid = threadIdx.x;
    size_t baseQ = ((size_t)b * SEQ) * QKVN + h * 64;

    for (int idx = tid; idx < 49 * 64; idx += 256) {
        int j = idx >> 6, d = idx & 63;
        int sp = (j == 0) ? 0 : (typ == 0 ? 1 + n * 48 + (j - 1) : 1 + (j - 1) * 48 + n);
        size_t base = baseQ + (size_t)sp * QKVN + d;
        kl[j * 65 + d] = qkv[base + 512];
        vl[j * 65 + d] = qkv[base + 1024];
    }
    __syncthreads();

    int wave = tid >> 6, lane = tid & 63;
    const float NEG_INF = -__builtin_inff();
    for (int i = 1 + wave; i <= 48; i += 4) {
        int sp = typ == 0 ? 1 + n * 48 + (i - 1) : 1 + (i - 1) * 48 + n;
        const float* qrow = qkv + baseQ + (size_t)sp * QKVN;
        float dot;
        if (lane <= i) {
            float s = 0.f;
            const float* kr = &kl[lane * 65];
            #pragma unroll 8
            for (int d = 0; d < 64; d++) s += qrow[d] * kr[d];
            dot = s * 0.125f;
        } else dot = NEG_INF;
        float m = wave_max(dot);
        float e = __expf(dot - m);
        float ssum = wave_sum(e);
        pl[wave][lane] = e / ssum;
        float acc = 0.f;
        int d = lane;
        for (int j = 0; j <= i; j++) acc += pl[wave][j] * vl[j * 65 + d];
        attn_b[((size_t)b * SEQ + sp) * DIM + h * 64 + d] = __float2bfloat16(acc);
    }
    if (n == 0 && tid < 64) {
        // bos output = v_bos (softmax over single unmasked key)
        attn_b[((size_t)b * SEQ) * DIM + h * 64 + tid] =
            __float2bfloat16(qkv[baseQ + 1024 + tid]);
    }
}

// ---------------- nearby attention (geometric sparse mask) ----------------
// one wave per (qp, b, h): grid 9220 blocks * 4 waves = 2305*16.
__global__ __launch_bounds__(256) void nearby_attn(
    const float* __restrict__ qkv, __hip_bfloat16* __restrict__ attn_b) {
    __shared__ float pl[4][128];
    __shared__ int kpl[4][128];
    int tid = threadIdx.x;
    int wave = tid >> 6, lane = tid & 63;
    int wgid = blockIdx.x * 4 + wave;
    int qp = wgid >> 4;
    int bh = wgid & 15;
    int b = bh >> 3, h = bh & 7;
    size_t base = ((size_t)b * SEQ) * QKVN + h * 64;
    size_t outIdx = ((size_t)b * SEQ + qp) * DIM + h * 64 + lane;

    if (qp == 0) {   // attends only to itself -> v[0]
        attn_b[outIdx] = __float2bfloat16(qkv[base + 1024 + lane]);
        return;
    }
    if (qp == 2304) {  // all-masked row -> uniform softmax -> mean of all V
        float acc = 0.f;
        for (int j = 0; j < SEQ; j++) acc += qkv[base + (size_t)j * QKVN + 1024 + lane];
        attn_b[outIdx] = __float2bfloat16(acc * (1.0f / 2305.0f));
        return;
    }

    int i2 = qp;  // mask row of token qp (roll -1 quirk), qp in [1,2303]
    int t = i2 >> 8, r = i2 & 255, hh = r >> 4, ww = r & 15;
    int t0 = t > 3 ? t - 3 : 0;
    int nf = t - t0 + 1;
    int nc = nf * 25;
    const float* qrow = qkv + base + (size_t)qp * QKVN;

    int kp1 = 0, kp2 = 0;
    bool v1 = false, v2 = false;
    {
        int c = lane;
        if (c < nc) {
            int f = c / 25, pos = c % 25;
            int tt = t0 + f, dy = pos / 5 - 2, dx = pos % 5 - 2;
            int h2 = hh + dy, w2 = ww + dx;
            if (h2 >= 0 && h2 < 16 && w2 >= 0 && w2 < 16 && (tt < t || pos < 12)) {
                kp1 = tt * 256 + h2 * 16 + w2 + 1; v1 = true;
            }
        }
        c = lane + 64;
        if (c < nc) {
            int f = c / 25, pos = c % 25;
            int tt = t0 + f, dy = pos / 5 - 2, dx = pos % 5 - 2;
            int h2 = hh + dy, w2 = ww + dx;
            if (h2 >= 0 && h2 < 16 && w2 >= 0 && w2 < 16 && (tt < t || pos < 12)) {
                kp2 = tt * 256 + h2 * 16 + w2 + 1; v2 = true;
            }
        }
    }
    const float* k1 = qkv + base + (size_t)kp1 * QKVN + 512;
    const float* k2 = qkv + base + (size_t)kp2 * QKVN + 512;
    float d1 = 0.f, d2 = 0.f;
    #pragma unroll 8
    for (int d = 0; d < 64; d++) {
        float qd = qrow[d];
        d1 += qd * k1[d];
        d2 += qd * k2[d];
    }
    const float NEG_INF = -__builtin_inff();
    d1 = v1 ? d1 * 0.125f : NEG_INF;
    d2 = v2 ? d2 * 0.125f : NEG_INF;
    float m = wave_max(fmaxf(d1, d2));
    float e1 = __expf(d1 - m), e2 = __expf(d2 - m);
    float s = wave_sum(e1 + e2);
    float inv = 1.0f / s;
    pl[wave][lane] = e1 * inv;       kpl[wave][lane] = kp1;
    pl[wave][lane + 64] = e2 * inv;  kpl[wave][lane + 64] = kp2;

    float acc = 0.f;
    for (int c = 0; c < nc; c++) {
        float pc = pl[wave][c];
        int kc = kpl[wave][c];
        acc += pc * qkv[base + (size_t)kc * QKVN + 1024 + lane];
    }
    attn_b[outIdx] = __float2bfloat16(acc);
}

// ---------------- host launch ----------------
extern "C" void kernel_launch(void* const* d_in, const int* in_sizes, int n_in,
                              void* d_out, int out_size, void* d_ws, size_t ws_size,
                              hipStream_t stream) {
    const float* x = (const float*)d_in[0];
    float* xcur = (float*)d_out;

    char* ws = (char*)d_ws;
    size_t off = 0;
    auto alloc = [&](size_t bytes) -> void* {
        void* p = ws + off;
        off = (off + bytes + 255) & ~(size_t)255;
        return p;
    };
    __hip_bfloat16* wqkv  = (__hip_bfloat16*)alloc((size_t)3 * QKVN * DIM * 2);
    __hip_bfloat16* wo    = (__hip_bfloat16*)alloc((size_t)3 * DIM * DIM * 2);
    __hip_bfloat16* xb    = (__hip_bfloat16*)alloc((size_t)NROWS * DIM * 2);
    __hip_bfloat16* attnb = (__hip_bfloat16*)alloc((size_t)NROWS * DIM * 2);
    float* qkv            = (float*)alloc((size_t)NROWS * QKVN * 4);

    const int nElem = NROWS * DIM;         // 2360320
    const int n4 = nElem / 4;

    copy_f32v4<<<(n4 + 255) / 256, 256, 0, stream>>>((const float4*)x, (float4*)xcur, n4);

    WPack wp;
    for (int l = 0; l < 3; l++)
        for (int j = 0; j < 4; j++)
            wp.p[l * 4 + j] = (const float*)d_in[2 + l * 5 + j];
    transpose_weights<<<dim3(16, 16, 12), dim3(32, 8), 0, stream>>>(wp, wqkv, wo);

    for (int l = 0; l < 3; l++) {
        f32_to_bf16<<<(nElem + 255) / 256, 256, 0, stream>>>(xcur, xb, nElem);
        gemm_bf16<<<dim3((NROWS + 63) / 64, QKVN / 64), 256, 0, stream>>>(
            xb, wqkv + (size_t)l * QKVN * DIM, qkv, nullptr, nullptr, NROWS, QKVN);
        if (l < 2)
            axial_attn<<<dim3(48, 16), 256, 0, stream>>>(qkv, attnb, l);
        else
            nearby_attn<<<(SEQ * 16) / 4, 256, 0, stream>>>(qkv, attnb);
        const float* bo = (const float*)d_in[6 + l * 5];
        gemm_bf16<<<dim3((NROWS + 63) / 64, DIM / 64), 256, 0, stream>>>(
            attnb, wo + (size_t)l * DIM * DIM, xcur, bo, xcur, NROWS, DIM);
    }
}